// Round 19
// baseline (221.378 us; speedup 1.0000x reference)
//
#include <hip/hip_runtime.h>
#include <cstdint>
#include <cstddef>

#define T_SEQ 2048
#define DMODEL 2048
#define HQ 16
#define HKV 4
#define HD 128

typedef __attribute__((ext_vector_type(4))) float f32x4;
typedef __attribute__((ext_vector_type(8))) short bf16x8;
typedef __attribute__((ext_vector_type(4))) short short4v;
typedef __attribute__((ext_vector_type(2))) short short2v;
typedef __attribute__((ext_vector_type(4))) unsigned uint4v;

__device__ __forceinline__ short f2bf(float f) {
  unsigned u = __builtin_bit_cast(unsigned, f);
  u = (u + 0x7FFFu + ((u >> 16) & 1u)) >> 16;
  return (short)u;
}
__device__ __forceinline__ float bf2f(short s) {
  unsigned u = ((unsigned)(unsigned short)s) << 16;
  return __builtin_bit_cast(float, u);
}
// pack hi16(a) | hi16(b)<<16 (bf16 truncation) in ONE v_perm_b32
__device__ __forceinline__ unsigned pk_hi16(float a, float b) {
  return __builtin_amdgcn_perm(__builtin_bit_cast(unsigned, b),
                               __builtin_bit_cast(unsigned, a), 0x07060302u);
}

__device__ __forceinline__ void g2lds16(const void* g, void* l) {
  __builtin_amdgcn_global_load_lds(
      (const __attribute__((address_space(1))) void*)g,
      (__attribute__((address_space(3))) void*)l, 16, 0, 0);
}

// ---------------- fused prep: 4 weight transposes + x convert, ONE launch ----------------
__global__ void prep_kernel(const float* __restrict__ s0, const float* __restrict__ s1,
                            const float* __restrict__ s2, const float* __restrict__ s3,
                            const float* __restrict__ xs,
                            short* __restrict__ d0, short* __restrict__ d1,
                            short* __restrict__ d2, short* __restrict__ d3,
                            short* __restrict__ xd) {
  const int z = blockIdx.z;
  const int tx = threadIdx.x, ty = threadIdx.y;
  if (z == 4) {
    int bid = blockIdx.y * 64 + blockIdx.x;
    int tid = ty * 32 + tx;
    size_t base = ((size_t)bid * 256 + tid) * 8;
    float4 v0 = *(const float4*)(xs + base);
    float4 v1 = *(const float4*)(xs + base + 4);
    short4v o0, o1;
    o0[0] = f2bf(v0.x); o0[1] = f2bf(v0.y); o0[2] = f2bf(v0.z); o0[3] = f2bf(v0.w);
    o1[0] = f2bf(v1.x); o1[1] = f2bf(v1.y); o1[2] = f2bf(v1.z); o1[3] = f2bf(v1.w);
    *(short4v*)(xd + base) = o0;
    *(short4v*)(xd + base + 4) = o1;
    return;
  }
  __shared__ float tile[32][33];
  const float* src = (z == 0) ? s0 : (z == 1) ? s1 : (z == 2) ? s2 : s3;
  short* dst = (z == 0) ? d0 : (z == 1) ? d1 : (z == 2) ? d2 : d3;
  const int C = (z == 1 || z == 2) ? 512 : 2048;
  const int R = 2048;
  int c0 = blockIdx.x * 32, r0 = blockIdx.y * 32;
  if (c0 >= C) return;
  #pragma unroll
  for (int i = 0; i < 32; i += 8)
    tile[ty + i][tx] = src[(size_t)(r0 + ty + i) * C + c0 + tx];
  __syncthreads();
  #pragma unroll
  for (int i = 0; i < 32; i += 8)
    dst[(size_t)(c0 + ty + i) * R + r0 + tx] = f2bf(tile[tx][ty + i]);
}

// ---------------- GEMM: m97 2-barrier skeleton, BK=64 + FUSED ROPE + XCD swizzle ----------------
template <int MODE>
__global__ __launch_bounds__(256, 2) void gemm_kernel(
    const short* __restrict__ A, const short* __restrict__ BT,
    void* __restrict__ C0, void* __restrict__ C1, void* __restrict__ C2,
    int M, int N, int K)
{
  __shared__ short As[128 * 64];   // 16 KB
  __shared__ short Bs[128 * 64];   // 16 KB
  const int tid = threadIdx.x;
  const int lane = tid & 63, w = tid >> 6;
  const int l15 = lane & 15, g = lane >> 4;

  // XCD-chunked block swizzle (bijective: grid size divisible by 8)
  const int nbx = gridDim.x;
  const int lid = blockIdx.y * nbx + blockIdx.x;
  const int nwg = nbx * gridDim.y;
  const int cpx = nwg >> 3;
  const int swz = (lid & 7) * cpx + (lid >> 3);
  const int m0 = (swz / nbx) * 128, n0 = (swz % nbx) * 128;

  const int wm = (w >> 1) * 64;
  const int wn32 = (w & 1) * 32;

  const int srow = tid >> 3;
  const int sc   = tid & 7;

  f32x4 acc[4][4] = {};

  for (int k0 = 0; k0 < K; k0 += 64) {
    __syncthreads();
    #pragma unroll
    for (int call = 0; call < 4; call++) {
      int row = call * 32 + srow;
      int csw = sc ^ (row & 7);
      g2lds16(A + (size_t)(m0 + row) * K + k0 + csw * 8,
              (char*)As + call * 4096 + w * 1024);
      g2lds16(BT + (size_t)(n0 + row) * K + k0 + csw * 8,
              (char*)Bs + call * 4096 + w * 1024);
    }
    __syncthreads();
    #pragma unroll
    for (int kk = 0; kk < 2; kk++) {
      bf16x8 af[4], bfr[4];
      #pragma unroll
      for (int mi = 0; mi < 4; mi++) {
        int row = wm + mi * 16 + l15;
        int ch = (kk * 4 + g) ^ (row & 7);
        af[mi] = *(const bf16x8*)(As + row * 64 + ch * 8);
      }
      #pragma unroll
      for (int ni = 0; ni < 4; ni++) {
        int row = wn32 + (ni & 1) * 16 + (ni >> 1) * 64 + l15;   // co(ni) mapping
        int ch = (kk * 4 + g) ^ (row & 7);
        bfr[ni] = *(const bf16x8*)(Bs + row * 64 + ch * 8);
      }
      #pragma unroll
      for (int mi = 0; mi < 4; mi++)
        #pragma unroll
        for (int ni = 0; ni < 4; ni++)
          acc[mi][ni] = __builtin_amdgcn_mfma_f32_16x16x32_bf16(af[mi], bfr[ni], acc[mi][ni], 0, 0, 0);
    }
  }

  if (MODE == 1) {
    float* C = (float*)C0;
    #pragma unroll
    for (int mi = 0; mi < 4; mi++)
      #pragma unroll
      for (int r = 0; r < 4; r++) {
        int m = m0 + wm + mi * 16 + g * 4 + r;
        #pragma unroll
        for (int ni = 0; ni < 4; ni++) {
          int col = n0 + wn32 + (ni & 1) * 16 + (ni >> 1) * 64 + l15;
          C[(size_t)m * N + col] = acc[mi][ni][r];
        }
      }
  } else {
    short* Cb; int ldc, nc, rmode;       // rmode: 0=v (no rope), 1=k, 2=q
    if (n0 < 2048)      { Cb = (short*)C0; ldc = 2048; nc = n0;        rmode = 2; }
    else if (n0 < 2560) { Cb = (short*)C1; ldc = 512;  nc = n0 - 2048; rmode = 1; }
    else                { Cb = (short*)C2; ldc = 512;  nc = n0 - 2560; rmode = 0; }

    if (rmode) {
      const float scale = (rmode == 2) ? 0.12754448602243686f   // MULT * log2(e)
                                       : 1.0f;
      #pragma unroll
      for (int np = 0; np < 2; np++) {
        int i = wn32 + np * 16 + l15;                   // d within head, < 64
        float invf = exp2f(-(float)i * 0.20762050593046014f);  // 10000^(-i/64)
        #pragma unroll
        for (int mi = 0; mi < 4; mi++)
          #pragma unroll
          for (int r = 0; r < 4; r++) {
            int m = m0 + wm + mi * 16 + g * 4 + r;
            float theta = (float)(m & 2047) * invf;
            float sn, cs;
            __sincosf(theta, &sn, &cs);
            float lo = acc[mi][np][r], hi = acc[mi][np + 2][r];
            Cb[(size_t)m * ldc + nc + i]      = f2bf((lo * cs - hi * sn) * scale);
            Cb[(size_t)m * ldc + nc + 64 + i] = f2bf((hi * cs + lo * sn) * scale);
          }
      }
    } else {
      #pragma unroll
      for (int mi = 0; mi < 4; mi++)
        #pragma unroll
        for (int r = 0; r < 4; r++) {
          int m = m0 + wm + mi * 16 + g * 4 + r;
          #pragma unroll
          for (int ni = 0; ni < 4; ni++) {
            int col = nc + wn32 + (ni & 1) * 16 + (ni >> 1) * 64 + l15;
            Cb[(size_t)m * ldc + col] = f2bf(acc[mi][ni][r]);
          }
        }
    }
  }
}

// ---------------- Flash attention: 256 q-rows/block (8 waves x 32q, qc=2) + kv-parity split ----
// Grid (16,16,2): x = qx*2+hf, qti = b ? 7-qx : qx (uniform per-CU pairing: 18 tile-units).
// 512 thr = 8 waves; wave w owns q rows [qti*256 + w*32, +32) via qc=2 subtiles.
// K dbuf via global_load_lds + V^T single-buffered split staging (r5 staging, r10 compute).
// hf processes kv tiles t = hf, hf+2, ... ; hf=0 writes og + stats, hf=1 writes pOn + stats.
__global__ __launch_bounds__(512, 2) void attn_kernel(
    const short* __restrict__ qg, const short* __restrict__ kg,
    const short* __restrict__ vg, short* __restrict__ og,
    short* __restrict__ pOn, float2* __restrict__ ml)
{
  __shared__ short Ks[2][64 * 128];  // 32 KB
  __shared__ short Vt[128 * 64];     // 16 KB
  const int tid = threadIdx.x;
  const int lane = tid & 63, w = tid >> 6;          // 8 waves
  const int l15 = lane & 15, g = lane >> 4;
  const int b = blockIdx.z;
  const int qx = blockIdx.x >> 1, hf = blockIdx.x & 1;
  const int qti = b ? (7 - qx) : qx;                // causal pairing balance
  const int qt0 = qti * 256;
  const int h = blockIdx.y, hk = h >> 2;
  const int qw0 = qt0 + w * 32;                     // 32 q-rows per wave

  // Q fragments: [qc][ks], lane holds Q[q=qw0+qc*16+l15][d=(ks*4+g)*8 ..+7]
  bf16x8 qf[2][4];
  #pragma unroll
  for (int qc = 0; qc < 2; qc++) {
    size_t t = (size_t)b * T_SEQ + qw0 + qc * 16 + l15;
    const short* qp = qg + (t * HQ + h) * HD;
    #pragma unroll
    for (int ks = 0; ks < 4; ks++)
      qf[qc][ks] = *(const bf16x8*)(qp + ks * 32 + g * 8);
  }

  f32x4 of[2][8] = {};               // O^T acc [qc][dc]
  float m2[2] = {-INFINITY, -INFINITY};
  float ls[2] = {0.f, 0.f};          // per-lane partials (reduced at epilogue)

  const short* kbase = kg + ((size_t)b * T_SEQ * HKV + hk) * HD;
  const short* vbase = vg + ((size_t)b * T_SEQ * HKV + hk) * HD;

  // staging assignments (512 threads)
  const int kv2 = (tid & 31) * 2;
  const int d8s = (tid >> 5) * 8;
  const int p0 = (kv2 >> 5) * 32 + ((kv2 & 15) >> 2) * 8 + ((kv2 >> 4) & 1) * 4 + (kv2 & 3);
  const int ntAll = 4 * qti + 4;     // kv tiles of 64 covering rows < qt0+256

  bf16x8 vr[2];

  auto stageK = [&](int t, int nb) {
    #pragma unroll
    for (int call = 0; call < 2; call++) {
      int tau = call * 512 + tid;
      int kv = tau >> 4, c = tau & 15;
      g2lds16(kbase + (size_t)(t * 64 + kv) * (HKV * HD) + ((c ^ (kv & 7)) << 3),
              (char*)Ks[nb] + call * 8192 + w * 1024);
    }
  };
  auto loadV = [&](int t) {
    const short* vp = vbase + (size_t)(t * 64 + kv2) * (HKV * HD) + d8s;
    vr[0] = *(const bf16x8*)(vp);
    vr[1] = *(const bf16x8*)(vp + HKV * HD);
  };
  auto writeV = [&]() {
    #pragma unroll
    for (int e = 0; e < 8; e++) {
      int row = d8s + e;
      int addr = row * 64 + (((p0 >> 3) ^ e) << 3) + (p0 & 7);
      short2v t2; t2[0] = vr[0][e]; t2[1] = vr[1][e];
      *(short2v*)(&Vt[addr]) = t2;
    }
  };

  // prologue: first tile (index hf) into buffer 0
  stageK(hf, 0);
  loadV(hf);
  __syncthreads();                    // K staged; vr valid
  writeV();
  __syncthreads();                    // Vt visible

  int buf = 0;
  for (int t = hf; t < ntAll; t += 2) {
    const int kv0 = t * 64;
    const int tn = t + 2;
    const bool haveNext = (tn < ntAll);
    if (haveNext) { loadV(tn); stageK(tn, buf ^ 1); }

    if (kv0 <= qw0 + 31) {
      const short* Kc = Ks[buf];
      f32x4 sacc[4][2] = {};
      __builtin_amdgcn_s_setprio(1);
      #pragma unroll
      for (int ks = 0; ks < 4; ks++) {
        bf16x8 kf[4];
        #pragma unroll
        for (int kt = 0; kt < 4; kt++) {
          int row = kt * 16 + l15;
          int ch = (ks * 4 + g) ^ (row & 7);
          kf[kt] = *(const bf16x8*)(Kc + row * 128 + ch * 8);
        }
        #pragma unroll
        for (int kt = 0; kt < 4; kt++)
          #pragma unroll
          for (int qc = 0; qc < 2; qc++)
            sacc[kt][qc] = __builtin_amdgcn_mfma_f32_16x16x32_bf16(kf[kt], qf[qc][ks], sacc[kt][qc], 0, 0, 0);
      }
      __builtin_amdgcn_s_setprio(0);
      const bool needmask = (kv0 + 63) > qw0;
      bf16x8 pb[2][2];                 // [ktw][qc]
      #pragma unroll
      for (int qc = 0; qc < 2; qc++) {
        int qpos = qw0 + qc * 16 + l15;
        float vmax = -INFINITY;
        #pragma unroll
        for (int kt = 0; kt < 4; kt++)
          #pragma unroll
          for (int r = 0; r < 4; r++) {
            int kvpos = kv0 + kt * 16 + g * 4 + r;
            float sv = sacc[kt][qc][r];
            if (needmask && kvpos > qpos) sv = -INFINITY;
            sacc[kt][qc][r] = sv;
            vmax = fmaxf(vmax, sv);
          }
        vmax = fmaxf(vmax, __shfl_xor(vmax, 16));
        vmax = fmaxf(vmax, __shfl_xor(vmax, 32));
        if (!__all(vmax <= m2[qc] + 8.0f)) {   // defer-max (T13)
          float mnew = fmaxf(m2[qc], vmax);
          float resc = exp2f(m2[qc] - mnew);
          m2[qc] = mnew;
          ls[qc] *= resc;                       // per-lane partial; resc lane-uniform
          #pragma unroll
          for (int dc = 0; dc < 8; dc++) of[qc][dc] *= resc;
        }
        float mref = m2[qc];
        #pragma unroll
        for (int kt = 0; kt < 4; kt++)
          #pragma unroll
          for (int r = 0; r < 4; r++) {
            float p = exp2f(sacc[kt][qc][r] - mref);
            sacc[kt][qc][r] = p;
            ls[qc] += p;                        // deferred cross-lane reduce
          }
        #pragma unroll
        for (int ktw = 0; ktw < 2; ktw++) {
          uint4v pw;
          pw[0] = pk_hi16(sacc[2 * ktw][qc][0], sacc[2 * ktw][qc][1]);
          pw[1] = pk_hi16(sacc[2 * ktw][qc][2], sacc[2 * ktw][qc][3]);
          pw[2] = pk_hi16(sacc[2 * ktw + 1][qc][0], sacc[2 * ktw + 1][qc][1]);
          pw[3] = pk_hi16(sacc[2 * ktw + 1][qc][2], sacc[2 * ktw + 1][qc][3]);
          pb[ktw][qc] = __builtin_bit_cast(bf16x8, pw);
        }
      }
      // O^T += V^T * P : one swizzled ds_read_b128 per fragment, shared by qc pair
      __builtin_amdgcn_s_setprio(1);
      #pragma unroll
      for (int ktw = 0; ktw < 2; ktw++)
        #pragma unroll
        for (int dc = 0; dc < 8; dc++) {
          int row = dc * 16 + l15;
          bf16x8 vf = *(const bf16x8*)(&Vt[row * 64 + ((ktw * 32 + g * 8) ^ ((l15 & 7) << 3))]);
          #pragma unroll
          for (int qc = 0; qc < 2; qc++)
            of[qc][dc] = __builtin_amdgcn_mfma_f32_16x16x32_bf16(vf, pb[ktw][qc], of[qc][dc], 0, 0, 0);
        }
      __builtin_amdgcn_s_setprio(0);
    }

    __syncthreads();                 // reads of Vt/Ks[buf] done; prefetch drained
    if (haveNext) writeV();
    __syncthreads();                 // Vt(next) visible
    buf ^= 1;
  }

  // epilogue: reduce ls across g-lanes, normalize, store (og for hf=0, pOn for hf=1) + stats
  #pragma unroll
  for (int qc = 0; qc < 2; qc++) {
    float lss = ls[qc];
    lss += __shfl_xor(lss, 16);
    lss += __shfl_xor(lss, 32);
    float inv = lss > 0.f ? 1.0f / lss : 0.f;
    const int q = qw0 + qc * 16 + l15;
    size_t row = (size_t)(b * 16 + h) * 2048 + q;
    short* op = (hf == 0) ? (og + (((size_t)b * T_SEQ + q) * HQ + h) * HD)
                          : (pOn + row * 128);
    #pragma unroll
    for (int dc = 0; dc < 8; dc++) {
      short4v o;
      #pragma unroll
      for (int r = 0; r < 4; r++) o[r] = f2bf(of[qc][dc][r] * inv);
      *(short4v*)(op + dc * 16 + g * 4) = o;
    }
    if (g == 0) {
      float2 st; st.x = m2[qc]; st.y = lss;
      ml[(size_t)hf * 65536 + row] = st;
    }
  }
}

// ---------------- combine kv-parity partials: ab (hf=0) + pOn (hf=1) -> ab ----------------
__global__ void combine_kernel(const short* __restrict__ pOn, const float2* __restrict__ ml,
                               short* __restrict__ ab) {
  int idx = blockIdx.x * 256 + threadIdx.x;   // 2,097,152 threads
  int d4 = (idx & 31) * 4;
  int r = idx >> 5;                           // (b*16+h)*2048 + q
  int q = r & 2047, bh = r >> 11;
  float2 s0 = ml[r], s1 = ml[65536 + r];
  float M = fmaxf(s0.x, s1.x);
  float w0 = s0.y * exp2f(s0.x - M);
  float w1 = s1.y * exp2f(s1.x - M);
  float inv = 1.0f / (w0 + w1);
  w0 *= inv; w1 *= inv;
  int bb = bh >> 4, hh = bh & 15;
  size_t aoff = ((size_t)(bb * T_SEQ + q) * HQ + hh) * HD + d4;
  short4v a = *(const short4v*)(ab + aoff);
  short4v c = *(const short4v*)(pOn + (size_t)r * 128 + d4);
  short4v o;
  #pragma unroll
  for (int j = 0; j < 4; j++) o[j] = f2bf(w0 * bf2f(a[j]) + w1 * bf2f(c[j]));
  *(short4v*)(ab + aoff) = o;
}

extern "C" void kernel_launch(void* const* d_in, const int* in_sizes, int n_in,
                              void* d_out, int out_size, void* d_ws, size_t ws_size,
                              hipStream_t stream) {
  (void)in_sizes; (void)n_in; (void)out_size; (void)ws_size;
  const float* x  = (const float*)d_in[0];
  const float* Wq = (const float*)d_in[2];
  const float* Wk = (const float*)d_in[3];
  const float* Wv = (const float*)d_in[4];
  const float* Wo = (const float*)d_in[5];

  char* ws = (char*)d_ws;
  // phase-1 overlays (dead after QKV GEMM):
  short*  xb   = (short*)(ws);                   // [0,16M)
  short*  wall = (short*)(ws + 16777216);        // [16M,29.4M) WqT|WkT|WvT
  short*  wkT  = wall + (size_t)2048 * 2048;
  short*  wvT  = wall + (size_t)2560 * 2048;
  // phase-2 overlays (attn partials; reuse xb/wall space):
  short*  pOn  = (short*)(ws);                   // [0,16M)  hf=1 partial O
  float2* ml   = (float2*)(ws + 16777216);       // [16M,17M) stats [2][65536]
  // persistent:
  short*  woT  = (short*)(ws + 29360128);        // 8 MB
  short*  qb   = (short*)(ws + 37748736);        // 16 MB [B,T,HQ,128]
  short*  kb   = (short*)(ws + 54525952);        // 4 MB  [B,T,HKV,128]
  short*  vb   = (short*)(ws + 58720256);        // 4 MB  [B,T,HKV,128]
  short*  ab   = (short*)(ws + 62914560);        // 16 MB [4096][2048]

  dim3 tb(32, 8);
  // fused prep: weight transposes + x conversion in one launch
  prep_kernel<<<dim3(64, 64, 5), tb, 0, stream>>>(Wq, Wk, Wv, Wo, x,
                                                  wall, wkT, wvT, woT, xb);

  // fused QKV projection + RoPE: [4096][2048] x [2048][3072] -> qb|kb|vb (roped, q scaled)
  gemm_kernel<2><<<dim3(24, 32), 256, 0, stream>>>(xb, wall, qb, kb, vb, 4096, 3072, 2048);

  attn_kernel<<<dim3(16, 16, 2), 512, 0, stream>>>(qb, kb, vb, ab, pOn, ml);
  combine_kernel<<<8192, 256, 0, stream>>>(pOn, ml, ab);

  gemm_kernel<1><<<dim3(16, 32), 256, 0, stream>>>(ab, woT, d_out, nullptr, nullptr, 4096, 2048, 2048);
}

// Round 20
// 190.639 us; speedup vs baseline: 1.1612x; 1.1612x over previous
//
#include <hip/hip_runtime.h>
#include <cstdint>
#include <cstddef>

#define T_SEQ 2048
#define DMODEL 2048
#define HQ 16
#define HKV 4
#define HD 128

typedef __attribute__((ext_vector_type(4))) float f32x4;
typedef __attribute__((ext_vector_type(8))) short bf16x8;
typedef __attribute__((ext_vector_type(4))) short short4v;
typedef __attribute__((ext_vector_type(2))) short short2v;
typedef __attribute__((ext_vector_type(4))) unsigned uint4v;

__device__ __forceinline__ short f2bf(float f) {
  unsigned u = __builtin_bit_cast(unsigned, f);
  u = (u + 0x7FFFu + ((u >> 16) & 1u)) >> 16;
  return (short)u;
}
__device__ __forceinline__ float bf2f(short s) {
  unsigned u = ((unsigned)(unsigned short)s) << 16;
  return __builtin_bit_cast(float, u);
}
// pack hi16(a) | hi16(b)<<16 (bf16 truncation) in ONE v_perm_b32
__device__ __forceinline__ unsigned pk_hi16(float a, float b) {
  return __builtin_amdgcn_perm(__builtin_bit_cast(unsigned, b),
                               __builtin_bit_cast(unsigned, a), 0x07060302u);
}

__device__ __forceinline__ void g2lds16(const void* g, void* l) {
  __builtin_amdgcn_global_load_lds(
      (const __attribute__((address_space(1))) void*)g,
      (__attribute__((address_space(3))) void*)l, 16, 0, 0);
}

// ---------------- fused prep: 4 weight transposes + x convert, ONE launch ----------------
__global__ void prep_kernel(const float* __restrict__ s0, const float* __restrict__ s1,
                            const float* __restrict__ s2, const float* __restrict__ s3,
                            const float* __restrict__ xs,
                            short* __restrict__ d0, short* __restrict__ d1,
                            short* __restrict__ d2, short* __restrict__ d3,
                            short* __restrict__ xd) {
  const int z = blockIdx.z;
  const int tx = threadIdx.x, ty = threadIdx.y;
  if (z == 4) {
    int bid = blockIdx.y * 64 + blockIdx.x;
    int tid = ty * 32 + tx;
    size_t base = ((size_t)bid * 256 + tid) * 8;
    float4 v0 = *(const float4*)(xs + base);
    float4 v1 = *(const float4*)(xs + base + 4);
    short4v o0, o1;
    o0[0] = f2bf(v0.x); o0[1] = f2bf(v0.y); o0[2] = f2bf(v0.z); o0[3] = f2bf(v0.w);
    o1[0] = f2bf(v1.x); o1[1] = f2bf(v1.y); o1[2] = f2bf(v1.z); o1[3] = f2bf(v1.w);
    *(short4v*)(xd + base) = o0;
    *(short4v*)(xd + base + 4) = o1;
    return;
  }
  __shared__ float tile[32][33];
  const float* src = (z == 0) ? s0 : (z == 1) ? s1 : (z == 2) ? s2 : s3;
  short* dst = (z == 0) ? d0 : (z == 1) ? d1 : (z == 2) ? d2 : d3;
  const int C = (z == 1 || z == 2) ? 512 : 2048;
  const int R = 2048;
  int c0 = blockIdx.x * 32, r0 = blockIdx.y * 32;
  if (c0 >= C) return;
  #pragma unroll
  for (int i = 0; i < 32; i += 8)
    tile[ty + i][tx] = src[(size_t)(r0 + ty + i) * C + c0 + tx];
  __syncthreads();
  #pragma unroll
  for (int i = 0; i < 32; i += 8)
    dst[(size_t)(c0 + ty + i) * R + r0 + tx] = f2bf(tile[tx][ty + i]);
}

// ---------------- GEMM: m97 2-barrier skeleton, BK=64 + FUSED ROPE + XCD swizzle ----------------
// C = A[M][K] * B, BT = B^T [N][K]. 256 thr = 4 waves (2x2), 128x128 tile.
// Block remap (T1): logical = (lid%8)*(nwg/8) + lid/8 — each XCD owns contiguous
// y-rows so A-panels are XCD-L2-local. Requires nwg % 8 == 0 (768, 512: both ok).
// Wave column mapping co(ni) = (w&1)*32 + (ni&1)*16 + (ni>>1)*64 -> RoPE pairs in-register.
template <int MODE>
__global__ __launch_bounds__(256, 2) void gemm_kernel(
    const short* __restrict__ A, const short* __restrict__ BT,
    void* __restrict__ C0, void* __restrict__ C1, void* __restrict__ C2,
    int M, int N, int K)
{
  __shared__ short As[128 * 64];   // 16 KB
  __shared__ short Bs[128 * 64];   // 16 KB
  const int tid = threadIdx.x;
  const int lane = tid & 63, w = tid >> 6;
  const int l15 = lane & 15, g = lane >> 4;

  // XCD-chunked block swizzle (bijective: grid size divisible by 8)
  const int nbx = gridDim.x;
  const int lid = blockIdx.y * nbx + blockIdx.x;
  const int nwg = nbx * gridDim.y;
  const int cpx = nwg >> 3;
  const int swz = (lid & 7) * cpx + (lid >> 3);
  const int m0 = (swz / nbx) * 128, n0 = (swz % nbx) * 128;

  const int wm = (w >> 1) * 64;
  const int wn32 = (w & 1) * 32;

  const int srow = tid >> 3;
  const int sc   = tid & 7;

  f32x4 acc[4][4] = {};

  for (int k0 = 0; k0 < K; k0 += 64) {
    __syncthreads();
    #pragma unroll
    for (int call = 0; call < 4; call++) {
      int row = call * 32 + srow;
      int csw = sc ^ (row & 7);
      g2lds16(A + (size_t)(m0 + row) * K + k0 + csw * 8,
              (char*)As + call * 4096 + w * 1024);
      g2lds16(BT + (size_t)(n0 + row) * K + k0 + csw * 8,
              (char*)Bs + call * 4096 + w * 1024);
    }
    __syncthreads();
    #pragma unroll
    for (int kk = 0; kk < 2; kk++) {
      bf16x8 af[4], bfr[4];
      #pragma unroll
      for (int mi = 0; mi < 4; mi++) {
        int row = wm + mi * 16 + l15;
        int ch = (kk * 4 + g) ^ (row & 7);
        af[mi] = *(const bf16x8*)(As + row * 64 + ch * 8);
      }
      #pragma unroll
      for (int ni = 0; ni < 4; ni++) {
        int row = wn32 + (ni & 1) * 16 + (ni >> 1) * 64 + l15;   // co(ni) mapping
        int ch = (kk * 4 + g) ^ (row & 7);
        bfr[ni] = *(const bf16x8*)(Bs + row * 64 + ch * 8);
      }
      #pragma unroll
      for (int mi = 0; mi < 4; mi++)
        #pragma unroll
        for (int ni = 0; ni < 4; ni++)
          acc[mi][ni] = __builtin_amdgcn_mfma_f32_16x16x32_bf16(af[mi], bfr[ni], acc[mi][ni], 0, 0, 0);
    }
  }

  if (MODE == 1) {
    float* C = (float*)C0;
    #pragma unroll
    for (int mi = 0; mi < 4; mi++)
      #pragma unroll
      for (int r = 0; r < 4; r++) {
        int m = m0 + wm + mi * 16 + g * 4 + r;
        #pragma unroll
        for (int ni = 0; ni < 4; ni++) {
          int col = n0 + wn32 + (ni & 1) * 16 + (ni >> 1) * 64 + l15;
          C[(size_t)m * N + col] = acc[mi][ni][r];
        }
      }
  } else {
    short* Cb; int ldc, nc, rmode;       // rmode: 0=v (no rope), 1=k, 2=q
    if (n0 < 2048)      { Cb = (short*)C0; ldc = 2048; nc = n0;        rmode = 2; }
    else if (n0 < 2560) { Cb = (short*)C1; ldc = 512;  nc = n0 - 2048; rmode = 1; }
    else                { Cb = (short*)C2; ldc = 512;  nc = n0 - 2560; rmode = 0; }

    if (rmode) {
      const float scale = (rmode == 2) ? 0.12754448602243686f   // MULT * log2(e)
                                       : 1.0f;
      #pragma unroll
      for (int np = 0; np < 2; np++) {
        int i = wn32 + np * 16 + l15;                   // d within head, < 64
        float invf = exp2f(-(float)i * 0.20762050593046014f);  // 10000^(-i/64)
        #pragma unroll
        for (int mi = 0; mi < 4; mi++)
          #pragma unroll
          for (int r = 0; r < 4; r++) {
            int m = m0 + wm + mi * 16 + g * 4 + r;
            float theta = (float)(m & 2047) * invf;
            float sn, cs;
            __sincosf(theta, &sn, &cs);
            float lo = acc[mi][np][r], hi = acc[mi][np + 2][r];
            Cb[(size_t)m * ldc + nc + i]      = f2bf((lo * cs - hi * sn) * scale);
            Cb[(size_t)m * ldc + nc + 64 + i] = f2bf((hi * cs + lo * sn) * scale);
          }
      }
    } else {
      #pragma unroll
      for (int mi = 0; mi < 4; mi++)
        #pragma unroll
        for (int r = 0; r < 4; r++) {
          int m = m0 + wm + mi * 16 + g * 4 + r;
          #pragma unroll
          for (int ni = 0; ni < 4; ni++) {
            int col = nc + wn32 + (ni & 1) * 16 + (ni >> 1) * 64 + l15;
            Cb[(size_t)m * ldc + col] = f2bf(acc[mi][ni][r]);
          }
        }
    }
  }
}

// ---------------- Flash attention (causal, GQA) — r5 config + deferred lsum (r15) ----------------
__global__ __launch_bounds__(512, 4) void attn_kernel(
    const short* __restrict__ qg, const short* __restrict__ kg,
    const short* __restrict__ vg, short* __restrict__ og)
{
  __shared__ short Ks[2][64 * 128];  // 32 KB
  __shared__ short Vt[128 * 64];     // 16 KB
  const int tid = threadIdx.x;
  const int lane = tid & 63, w = tid >> 6;          // 8 waves
  const int l15 = lane & 15, g = lane >> 4;
  const int b = blockIdx.z;
  const int qti = b ? (15 - (int)blockIdx.x) : (int)blockIdx.x;
  const int qt0 = qti * 128;
  const int h = blockIdx.y, hk = h >> 2;
  const int qw0 = qt0 + w * 16;

  bf16x8 qf[4];
  {
    size_t t = (size_t)b * T_SEQ + qw0 + l15;
    const short* qp = qg + (t * HQ + h) * HD;
    #pragma unroll
    for (int ks = 0; ks < 4; ks++)
      qf[ks] = *(const bf16x8*)(qp + ks * 32 + g * 8);
  }

  f32x4 of[8] = {};
  float m2 = -INFINITY;
  float ls = 0.f;                    // per-lane partial; reduced at epilogue

  const short* kbase = kg + ((size_t)b * T_SEQ * HKV + hk) * HD;
  const short* vbase = vg + ((size_t)b * T_SEQ * HKV + hk) * HD;

  const int kv2 = (tid & 31) * 2;
  const int d8s = (tid >> 5) * 8;
  const int p0 = (kv2 >> 5) * 32 + ((kv2 & 15) >> 2) * 8 + ((kv2 >> 4) & 1) * 4 + (kv2 & 3);
  const int nt = (qt0 + 128) >> 6;

  bf16x8 vr[2];

  auto stageK = [&](int t, int nb) {
    #pragma unroll
    for (int call = 0; call < 2; call++) {
      int tau = call * 512 + tid;
      int kv = tau >> 4, c = tau & 15;
      g2lds16(kbase + (size_t)(t * 64 + kv) * (HKV * HD) + ((c ^ (kv & 7)) << 3),
              (char*)Ks[nb] + call * 8192 + w * 1024);
    }
  };
  auto loadV = [&](int t) {
    const short* vp = vbase + (size_t)(t * 64 + kv2) * (HKV * HD) + d8s;
    vr[0] = *(const bf16x8*)(vp);
    vr[1] = *(const bf16x8*)(vp + HKV * HD);
  };
  auto writeV = [&]() {
    #pragma unroll
    for (int e = 0; e < 8; e++) {
      int row = d8s + e;
      int addr = row * 64 + (((p0 >> 3) ^ e) << 3) + (p0 & 7);
      short2v t2; t2[0] = vr[0][e]; t2[1] = vr[1][e];
      *(short2v*)(&Vt[addr]) = t2;
    }
  };

  stageK(0, 0);
  loadV(0);
  __syncthreads();
  writeV();
  __syncthreads();

  int cur = 0;
  for (int t = 0; t < nt; t++) {
    const int kv0 = t * 64;
    const bool haveNext = (t + 1 < nt);
    if (haveNext) { loadV(t + 1); stageK(t + 1, cur ^ 1); }

    if (kv0 <= qw0 + 15) {
      const short* Kc = Ks[cur];
      f32x4 sacc[4] = {};
      __builtin_amdgcn_s_setprio(1);
      #pragma unroll
      for (int ks = 0; ks < 4; ks++) {
        bf16x8 kf[4];
        #pragma unroll
        for (int kt = 0; kt < 4; kt++) {
          int row = kt * 16 + l15;
          int ch = (ks * 4 + g) ^ (row & 7);
          kf[kt] = *(const bf16x8*)(Kc + row * 128 + ch * 8);
        }
        #pragma unroll
        for (int kt = 0; kt < 4; kt++)
          sacc[kt] = __builtin_amdgcn_mfma_f32_16x16x32_bf16(kf[kt], qf[ks], sacc[kt], 0, 0, 0);
      }
      __builtin_amdgcn_s_setprio(0);
      const bool needmask = (kv0 + 63) > qw0;
      const int qpos = qw0 + l15;
      float vmax = -INFINITY;
      #pragma unroll
      for (int kt = 0; kt < 4; kt++)
        #pragma unroll
        for (int r = 0; r < 4; r++) {
          int kvpos = kv0 + kt * 16 + g * 4 + r;
          float sv = sacc[kt][r];
          if (needmask && kvpos > qpos) sv = -INFINITY;
          sacc[kt][r] = sv;
          vmax = fmaxf(vmax, sv);
        }
      vmax = fmaxf(vmax, __shfl_xor(vmax, 16));
      vmax = fmaxf(vmax, __shfl_xor(vmax, 32));
      if (!__all(vmax <= m2 + 8.0f)) {   // defer-max (T13)
        float mnew = fmaxf(m2, vmax);
        float resc = exp2f(m2 - mnew);
        m2 = mnew;
        ls *= resc;                       // per-lane partial; resc lane-uniform
        #pragma unroll
        for (int dc = 0; dc < 8; dc++) of[dc] *= resc;
      }
      #pragma unroll
      for (int kt = 0; kt < 4; kt++)
        #pragma unroll
        for (int r = 0; r < 4; r++) {
          float p = exp2f(sacc[kt][r] - m2);
          sacc[kt][r] = p;
          ls += p;                        // deferred: no per-tile shuffles
        }
      bf16x8 pb[2];
      #pragma unroll
      for (int ktw = 0; ktw < 2; ktw++) {
        uint4v pw;
        pw[0] = pk_hi16(sacc[2 * ktw][0], sacc[2 * ktw][1]);
        pw[1] = pk_hi16(sacc[2 * ktw][2], sacc[2 * ktw][3]);
        pw[2] = pk_hi16(sacc[2 * ktw + 1][0], sacc[2 * ktw + 1][1]);
        pw[3] = pk_hi16(sacc[2 * ktw + 1][2], sacc[2 * ktw + 1][3]);
        pb[ktw] = __builtin_bit_cast(bf16x8, pw);
      }
      __builtin_amdgcn_s_setprio(1);
      #pragma unroll
      for (int ktw = 0; ktw < 2; ktw++)
        #pragma unroll
        for (int dc = 0; dc < 8; dc++) {
          int row = dc * 16 + l15;
          bf16x8 vf = *(const bf16x8*)(&Vt[row * 64 + ((ktw * 32 + g * 8) ^ ((l15 & 7) << 3))]);
          of[dc] = __builtin_amdgcn_mfma_f32_16x16x32_bf16(vf, pb[ktw], of[dc], 0, 0, 0);
        }
      __builtin_amdgcn_s_setprio(0);
    }

    __syncthreads();
    if (haveNext) writeV();
    __syncthreads();
    cur ^= 1;
  }

  {
    ls += __shfl_xor(ls, 16);
    ls += __shfl_xor(ls, 32);
    float inv = 1.0f / ls;
    size_t t = (size_t)b * T_SEQ + qw0 + l15;
    short* op = og + (t * HQ + h) * HD;
    #pragma unroll
    for (int dc = 0; dc < 8; dc++) {
      short4v o;
      #pragma unroll
      for (int r = 0; r < 4; r++) o[r] = f2bf(of[dc][r] * inv);
      *(short4v*)(op + dc * 16 + g * 4) = o;
    }
  }
}

extern "C" void kernel_launch(void* const* d_in, const int* in_sizes, int n_in,
                              void* d_out, int out_size, void* d_ws, size_t ws_size,
                              hipStream_t stream) {
  (void)in_sizes; (void)n_in; (void)out_size; (void)ws_size;
  const float* x  = (const float*)d_in[0];
  const float* Wq = (const float*)d_in[2];
  const float* Wk = (const float*)d_in[3];
  const float* Wv = (const float*)d_in[4];
  const float* Wo = (const float*)d_in[5];

  char* ws = (char*)d_ws;
  short* xb   = (short*)(ws);                    // 16 MB   [4096][2048]
  short* wall = (short*)(ws + 16777216);         // 12.6 MB [3072][2048] = WqT|WkT|WvT
  short* wkT  = wall + (size_t)2048 * 2048;
  short* wvT  = wall + (size_t)2560 * 2048;
  short* woT  = (short*)(ws + 29360128);         // 8 MB    [2048][2048]
  short* qb   = (short*)(ws + 37748736);         // 16 MB   [B,T,HQ,128]
  short* kb   = (short*)(ws + 54525952);         // 4 MB    [B,T,HKV,128]
  short* vb   = (short*)(ws + 58720256);         // 4 MB    [B,T,HKV,128]
  short* ab   = (short*)(ws + 62914560);         // 16 MB   [4096][2048]

  dim3 tb(32, 8);
  // fused prep: weight transposes + x conversion in one launch
  prep_kernel<<<dim3(64, 64, 5), tb, 0, stream>>>(Wq, Wk, Wv, Wo, x,
                                                  wall, wkT, wvT, woT, xb);

  // fused QKV projection + RoPE: [4096][2048] x [2048][3072] -> qb|kb|vb (roped, q scaled)
  gemm_kernel<2><<<dim3(24, 32), 256, 0, stream>>>(xb, wall, qb, kb, vb, 4096, 3072, 2048);

  attn_kernel<<<dim3(16, 16, 2), 512, 0, stream>>>(qb, kb, vb, ab);

  gemm_kernel<1><<<dim3(16, 32), 256, 0, stream>>>(ab, woT, d_out, nullptr, nullptr, 4096, 2048, 2048);
}

// Round 21
// 190.354 us; speedup vs baseline: 1.1630x; 1.0015x over previous
//
#include <hip/hip_runtime.h>
#include <cstdint>
#include <cstddef>

#define T_SEQ 2048
#define DMODEL 2048
#define HQ 16
#define HKV 4
#define HD 128

typedef __attribute__((ext_vector_type(4))) float f32x4;
typedef __attribute__((ext_vector_type(8))) short bf16x8;
typedef __attribute__((ext_vector_type(4))) short short4v;
typedef __attribute__((ext_vector_type(2))) short short2v;
typedef __attribute__((ext_vector_type(4))) unsigned uint4v;

#define SFEN() __builtin_amdgcn_sched_barrier(0)

__device__ __forceinline__ short f2bf(float f) {
  unsigned u = __builtin_bit_cast(unsigned, f);
  u = (u + 0x7FFFu + ((u >> 16) & 1u)) >> 16;
  return (short)u;
}
__device__ __forceinline__ float bf2f(short s) {
  unsigned u = ((unsigned)(unsigned short)s) << 16;
  return __builtin_bit_cast(float, u);
}
// pack hi16(a) | hi16(b)<<16 (bf16 truncation) in ONE v_perm_b32
__device__ __forceinline__ unsigned pk_hi16(float a, float b) {
  return __builtin_amdgcn_perm(__builtin_bit_cast(unsigned, b),
                               __builtin_bit_cast(unsigned, a), 0x07060302u);
}

__device__ __forceinline__ void g2lds16(const void* g, void* l) {
  __builtin_amdgcn_global_load_lds(
      (const __attribute__((address_space(1))) void*)g,
      (__attribute__((address_space(3))) void*)l, 16, 0, 0);
}

// ---------------- fused prep: 4 weight transposes + x convert, ONE launch ----------------
__global__ void prep_kernel(const float* __restrict__ s0, const float* __restrict__ s1,
                            const float* __restrict__ s2, const float* __restrict__ s3,
                            const float* __restrict__ xs,
                            short* __restrict__ d0, short* __restrict__ d1,
                            short* __restrict__ d2, short* __restrict__ d3,
                            short* __restrict__ xd) {
  const int z = blockIdx.z;
  const int tx = threadIdx.x, ty = threadIdx.y;
  if (z == 4) {
    int bid = blockIdx.y * 64 + blockIdx.x;
    int tid = ty * 32 + tx;
    size_t base = ((size_t)bid * 256 + tid) * 8;
    float4 v0 = *(const float4*)(xs + base);
    float4 v1 = *(const float4*)(xs + base + 4);
    short4v o0, o1;
    o0[0] = f2bf(v0.x); o0[1] = f2bf(v0.y); o0[2] = f2bf(v0.z); o0[3] = f2bf(v0.w);
    o1[0] = f2bf(v1.x); o1[1] = f2bf(v1.y); o1[2] = f2bf(v1.z); o1[3] = f2bf(v1.w);
    *(short4v*)(xd + base) = o0;
    *(short4v*)(xd + base + 4) = o1;
    return;
  }
  __shared__ float tile[32][33];
  const float* src = (z == 0) ? s0 : (z == 1) ? s1 : (z == 2) ? s2 : s3;
  short* dst = (z == 0) ? d0 : (z == 1) ? d1 : (z == 2) ? d2 : d3;
  const int C = (z == 1 || z == 2) ? 512 : 2048;
  const int R = 2048;
  int c0 = blockIdx.x * 32, r0 = blockIdx.y * 32;
  if (c0 >= C) return;
  #pragma unroll
  for (int i = 0; i < 32; i += 8)
    tile[ty + i][tx] = src[(size_t)(r0 + ty + i) * C + c0 + tx];
  __syncthreads();
  #pragma unroll
  for (int i = 0; i < 32; i += 8)
    dst[(size_t)(c0 + ty + i) * R + r0 + tx] = f2bf(tile[tx][ty + i]);
}

// ---------------- GEMM: m97 2-barrier skeleton, BK=64 + FUSED ROPE + XCD swizzle ----------------
template <int MODE>
__global__ __launch_bounds__(256, 2) void gemm_kernel(
    const short* __restrict__ A, const short* __restrict__ BT,
    void* __restrict__ C0, void* __restrict__ C1, void* __restrict__ C2,
    int M, int N, int K)
{
  __shared__ short As[128 * 64];   // 16 KB
  __shared__ short Bs[128 * 64];   // 16 KB
  const int tid = threadIdx.x;
  const int lane = tid & 63, w = tid >> 6;
  const int l15 = lane & 15, g = lane >> 4;

  // XCD-chunked block swizzle (bijective: grid size divisible by 8)
  const int nbx = gridDim.x;
  const int lid = blockIdx.y * nbx + blockIdx.x;
  const int nwg = nbx * gridDim.y;
  const int cpx = nwg >> 3;
  const int swz = (lid & 7) * cpx + (lid >> 3);
  const int m0 = (swz / nbx) * 128, n0 = (swz % nbx) * 128;

  const int wm = (w >> 1) * 64;
  const int wn32 = (w & 1) * 32;

  const int srow = tid >> 3;
  const int sc   = tid & 7;

  f32x4 acc[4][4] = {};

  for (int k0 = 0; k0 < K; k0 += 64) {
    __syncthreads();
    #pragma unroll
    for (int call = 0; call < 4; call++) {
      int row = call * 32 + srow;
      int csw = sc ^ (row & 7);
      g2lds16(A + (size_t)(m0 + row) * K + k0 + csw * 8,
              (char*)As + call * 4096 + w * 1024);
      g2lds16(BT + (size_t)(n0 + row) * K + k0 + csw * 8,
              (char*)Bs + call * 4096 + w * 1024);
    }
    __syncthreads();
    #pragma unroll
    for (int kk = 0; kk < 2; kk++) {
      bf16x8 af[4], bfr[4];
      #pragma unroll
      for (int mi = 0; mi < 4; mi++) {
        int row = wm + mi * 16 + l15;
        int ch = (kk * 4 + g) ^ (row & 7);
        af[mi] = *(const bf16x8*)(As + row * 64 + ch * 8);
      }
      #pragma unroll
      for (int ni = 0; ni < 4; ni++) {
        int row = wn32 + (ni & 1) * 16 + (ni >> 1) * 64 + l15;   // co(ni) mapping
        int ch = (kk * 4 + g) ^ (row & 7);
        bfr[ni] = *(const bf16x8*)(Bs + row * 64 + ch * 8);
      }
      #pragma unroll
      for (int mi = 0; mi < 4; mi++)
        #pragma unroll
        for (int ni = 0; ni < 4; ni++)
          acc[mi][ni] = __builtin_amdgcn_mfma_f32_16x16x32_bf16(af[mi], bfr[ni], acc[mi][ni], 0, 0, 0);
    }
  }

  if (MODE == 1) {
    float* C = (float*)C0;
    #pragma unroll
    for (int mi = 0; mi < 4; mi++)
      #pragma unroll
      for (int r = 0; r < 4; r++) {
        int m = m0 + wm + mi * 16 + g * 4 + r;
        #pragma unroll
        for (int ni = 0; ni < 4; ni++) {
          int col = n0 + wn32 + (ni & 1) * 16 + (ni >> 1) * 64 + l15;
          C[(size_t)m * N + col] = acc[mi][ni][r];
        }
      }
  } else {
    short* Cb; int ldc, nc, rmode;       // rmode: 0=v (no rope), 1=k, 2=q
    if (n0 < 2048)      { Cb = (short*)C0; ldc = 2048; nc = n0;        rmode = 2; }
    else if (n0 < 2560) { Cb = (short*)C1; ldc = 512;  nc = n0 - 2048; rmode = 1; }
    else                { Cb = (short*)C2; ldc = 512;  nc = n0 - 2560; rmode = 0; }

    if (rmode) {
      const float scale = (rmode == 2) ? 0.12754448602243686f   // MULT * log2(e)
                                       : 1.0f;
      #pragma unroll
      for (int np = 0; np < 2; np++) {
        int i = wn32 + np * 16 + l15;                   // d within head, < 64
        float invf = exp2f(-(float)i * 0.20762050593046014f);  // 10000^(-i/64)
        #pragma unroll
        for (int mi = 0; mi < 4; mi++)
          #pragma unroll
          for (int r = 0; r < 4; r++) {
            int m = m0 + wm + mi * 16 + g * 4 + r;
            float theta = (float)(m & 2047) * invf;
            float sn, cs;
            __sincosf(theta, &sn, &cs);
            float lo = acc[mi][np][r], hi = acc[mi][np + 2][r];
            Cb[(size_t)m * ldc + nc + i]      = f2bf((lo * cs - hi * sn) * scale);
            Cb[(size_t)m * ldc + nc + 64 + i] = f2bf((hi * cs + lo * sn) * scale);
          }
      }
    } else {
      #pragma unroll
      for (int mi = 0; mi < 4; mi++)
        #pragma unroll
        for (int r = 0; r < 4; r++) {
          int m = m0 + wm + mi * 16 + g * 4 + r;
          #pragma unroll
          for (int ni = 0; ni < 4; ni++) {
            int col = nc + wn32 + (ni & 1) * 16 + (ni >> 1) * 64 + l15;
            Cb[(size_t)m * ldc + col] = f2bf(acc[mi][ni][r]);
          }
        }
    }
  }
}

// ---------------- Flash attention (causal, GQA) — r15 config + T4 counted-vmcnt barriers ----
// Same structure as r15/r18 (91 us). ONLY change: per-tile __syncthreads (which drain
// vmcnt to 0, forcing the just-issued t+1 prefetch to land before writeV) are replaced by:
//   - vmcnt(4) before the K-fragment reads (4 newest = loadV(t+1)+stageK(t+1) stay in
//     flight; everything older — incl. stageK(t) feeding THIS tile — is forced complete)
//   - raw s_barrier for B1 (execution sync only; all Vt/Ks reads consumed by arrival)
//   - lgkmcnt(0) + raw s_barrier for B2 (Vt ds_writes visible)
// so the K-DMA for t+1 spans compute(t)+B1+writeV+B2 instead of just compute(t).
__global__ __launch_bounds__(512, 4) void attn_kernel(
    const short* __restrict__ qg, const short* __restrict__ kg,
    const short* __restrict__ vg, short* __restrict__ og)
{
  __shared__ short Ks[2][64 * 128];  // 32 KB
  __shared__ short Vt[128 * 64];     // 16 KB
  const int tid = threadIdx.x;
  const int lane = tid & 63, w = tid >> 6;          // 8 waves
  const int l15 = lane & 15, g = lane >> 4;
  const int b = blockIdx.z;
  const int qti = b ? (15 - (int)blockIdx.x) : (int)blockIdx.x;
  const int qt0 = qti * 128;
  const int h = blockIdx.y, hk = h >> 2;
  const int qw0 = qt0 + w * 16;

  bf16x8 qf[4];
  {
    size_t t = (size_t)b * T_SEQ + qw0 + l15;
    const short* qp = qg + (t * HQ + h) * HD;
    #pragma unroll
    for (int ks = 0; ks < 4; ks++)
      qf[ks] = *(const bf16x8*)(qp + ks * 32 + g * 8);
  }

  f32x4 of[8] = {};
  float m2 = -INFINITY;
  float ls = 0.f;                    // per-lane partial; reduced at epilogue

  const short* kbase = kg + ((size_t)b * T_SEQ * HKV + hk) * HD;
  const short* vbase = vg + ((size_t)b * T_SEQ * HKV + hk) * HD;

  const int kv2 = (tid & 31) * 2;
  const int d8s = (tid >> 5) * 8;
  const int p0 = (kv2 >> 5) * 32 + ((kv2 & 15) >> 2) * 8 + ((kv2 >> 4) & 1) * 4 + (kv2 & 3);
  const int nt = (qt0 + 128) >> 6;

  bf16x8 vr[2];

  auto stageK = [&](int t, int nb) {
    #pragma unroll
    for (int call = 0; call < 2; call++) {
      int tau = call * 512 + tid;
      int kv = tau >> 4, c = tau & 15;
      g2lds16(kbase + (size_t)(t * 64 + kv) * (HKV * HD) + ((c ^ (kv & 7)) << 3),
              (char*)Ks[nb] + call * 8192 + w * 1024);
    }
  };
  auto loadV = [&](int t) {
    const short* vp = vbase + (size_t)(t * 64 + kv2) * (HKV * HD) + d8s;
    vr[0] = *(const bf16x8*)(vp);
    vr[1] = *(const bf16x8*)(vp + HKV * HD);
  };
  auto writeV = [&]() {
    #pragma unroll
    for (int e = 0; e < 8; e++) {
      int row = d8s + e;
      int addr = row * 64 + (((p0 >> 3) ^ e) << 3) + (p0 & 7);
      short2v t2; t2[0] = vr[0][e]; t2[1] = vr[1][e];
      *(short2v*)(&Vt[addr]) = t2;
    }
  };

  // prologue (full drains — unchanged)
  stageK(0, 0);
  loadV(0);
  __syncthreads();
  writeV();
  __syncthreads();

  int cur = 0;
  for (int t = 0; t < nt; t++) {
    const int kv0 = t * 64;
    const bool haveNext = (t + 1 < nt);
    if (haveNext) { loadV(t + 1); stageK(t + 1, cur ^ 1); }

    if (kv0 <= qw0 + 15) {
      // ensure Ks[cur] (staged last iteration) has landed; keep the 4 newest
      // loads (loadV(t+1) x2 + stageK(t+1) x2) in flight across this tile.
      if (haveNext) { asm volatile("s_waitcnt vmcnt(4)" ::: "memory"); }
      else          { asm volatile("s_waitcnt vmcnt(0)" ::: "memory"); }
      SFEN();
      const short* Kc = Ks[cur];
      f32x4 sacc[4] = {};
      __builtin_amdgcn_s_setprio(1);
      #pragma unroll
      for (int ks = 0; ks < 4; ks++) {
        bf16x8 kf[4];
        #pragma unroll
        for (int kt = 0; kt < 4; kt++) {
          int row = kt * 16 + l15;
          int ch = (ks * 4 + g) ^ (row & 7);
          kf[kt] = *(const bf16x8*)(Kc + row * 128 + ch * 8);
        }
        #pragma unroll
        for (int kt = 0; kt < 4; kt++)
          sacc[kt] = __builtin_amdgcn_mfma_f32_16x16x32_bf16(kf[kt], qf[ks], sacc[kt], 0, 0, 0);
      }
      __builtin_amdgcn_s_setprio(0);
      const bool needmask = (kv0 + 63) > qw0;
      const int qpos = qw0 + l15;
      float vmax = -INFINITY;
      #pragma unroll
      for (int kt = 0; kt < 4; kt++)
        #pragma unroll
        for (int r = 0; r < 4; r++) {
          int kvpos = kv0 + kt * 16 + g * 4 + r;
          float sv = sacc[kt][r];
          if (needmask && kvpos > qpos) sv = -INFINITY;
          sacc[kt][r] = sv;
          vmax = fmaxf(vmax, sv);
        }
      vmax = fmaxf(vmax, __shfl_xor(vmax, 16));
      vmax = fmaxf(vmax, __shfl_xor(vmax, 32));
      if (!__all(vmax <= m2 + 8.0f)) {   // defer-max (T13)
        float mnew = fmaxf(m2, vmax);
        float resc = exp2f(m2 - mnew);
        m2 = mnew;
        ls *= resc;                       // per-lane partial; resc lane-uniform
        #pragma unroll
        for (int dc = 0; dc < 8; dc++) of[dc] *= resc;
      }
      #pragma unroll
      for (int kt = 0; kt < 4; kt++)
        #pragma unroll
        for (int r = 0; r < 4; r++) {
          float p = exp2f(sacc[kt][r] - m2);
          sacc[kt][r] = p;
          ls += p;                        // deferred: no per-tile shuffles
        }
      bf16x8 pb[2];
      #pragma unroll
      for (int ktw = 0; ktw < 2; ktw++) {
        uint4v pw;
        pw[0] = pk_hi16(sacc[2 * ktw][0], sacc[2 * ktw][1]);
        pw[1] = pk_hi16(sacc[2 * ktw][2], sacc[2 * ktw][3]);
        pw[2] = pk_hi16(sacc[2 * ktw + 1][0], sacc[2 * ktw + 1][1]);
        pw[3] = pk_hi16(sacc[2 * ktw + 1][2], sacc[2 * ktw + 1][3]);
        pb[ktw] = __builtin_bit_cast(bf16x8, pw);
      }
      __builtin_amdgcn_s_setprio(1);
      #pragma unroll
      for (int ktw = 0; ktw < 2; ktw++)
        #pragma unroll
        for (int dc = 0; dc < 8; dc++) {
          int row = dc * 16 + l15;
          bf16x8 vf = *(const bf16x8*)(&Vt[row * 64 + ((ktw * 32 + g * 8) ^ ((l15 & 7) << 3))]);
          of[dc] = __builtin_amdgcn_mfma_f32_16x16x32_bf16(vf, pb[ktw], of[dc], 0, 0, 0);
        }
      __builtin_amdgcn_s_setprio(0);
    }

    // B1: execution-only barrier (no vmcnt drain) — all waves consumed Vt/Ks[cur]
    SFEN();
    __builtin_amdgcn_s_barrier();
    SFEN();
    if (haveNext) writeV();            // compiler waits vr's 2 loads only
    // B2: Vt(t+1) ds_writes visible; K-DMA for t+1 may still be in flight
    asm volatile("s_waitcnt lgkmcnt(0)" ::: "memory");
    SFEN();
    __builtin_amdgcn_s_barrier();
    SFEN();
    cur ^= 1;
  }

  {
    ls += __shfl_xor(ls, 16);
    ls += __shfl_xor(ls, 32);
    float inv = 1.0f / ls;
    size_t t = (size_t)b * T_SEQ + qw0 + l15;
    short* op = og + (t * HQ + h) * HD;
    #pragma unroll
    for (int dc = 0; dc < 8; dc++) {
      short4v o;
      #pragma unroll
      for (int r = 0; r < 4; r++) o[r] = f2bf(of[dc][r] * inv);
      *(short4v*)(op + dc * 16 + g * 4) = o;
    }
  }
}

extern "C" void kernel_launch(void* const* d_in, const int* in_sizes, int n_in,
                              void* d_out, int out_size, void* d_ws, size_t ws_size,
                              hipStream_t stream) {
  (void)in_sizes; (void)n_in; (void)out_size; (void)ws_size;
  const float* x  = (const float*)d_in[0];
  const float* Wq = (const float*)d_in[2];
  const float* Wk = (const float*)d_in[3];
  const float* Wv = (const float*)d_in[4];
  const float* Wo = (const float*)d_in[5];

  char* ws = (char*)d_ws;
  short* xb   = (short*)(ws);                    // 16 MB   [4096][2048]
  short* wall = (short*)(ws + 16777216);         // 12.6 MB [3072][2048] = WqT|WkT|WvT
  short* wkT  = wall + (size_t)2048 * 2048;
  short* wvT  = wall + (size_t)2560 * 2048;
  short* woT  = (short*)(ws + 29360128);         // 8 MB    [2048][2048]
  short* qb   = (short*)(ws + 37748736);         // 16 MB   [B,T,HQ,128]
  short* kb   = (short*)(ws + 54525952);         // 4 MB    [B,T,HKV,128]
  short* vb   = (short*)(ws + 58720256);         // 4 MB    [B,T,HKV,128]
  short* ab   = (short*)(ws + 62914560);         // 16 MB   [4096][2048]

  dim3 tb(32, 8);
  // fused prep: weight transposes + x conversion in one launch
  prep_kernel<<<dim3(64, 64, 5), tb, 0, stream>>>(Wq, Wk, Wv, Wo, x,
                                                  wall, wkT, wvT, woT, xb);

  // fused QKV projection + RoPE: [4096][2048] x [2048][3072] -> qb|kb|vb (roped, q scaled)
  gemm_kernel<2><<<dim3(24, 32), 256, 0, stream>>>(xb, wall, qb, kb, vb, 4096, 3072, 2048);

  attn_kernel<<<dim3(16, 16, 2), 512, 0, stream>>>(qb, kb, vb, ab);

  gemm_kernel<1><<<dim3(16, 32), 256, 0, stream>>>(ab, woT, d_out, nullptr, nullptr, 4096, 2048, 2048);
}